// Round 3
// baseline (503.845 us; speedup 1.0000x reference)
//
#include <hip/hip_runtime.h>

#define CROP_H 14
#define CROP_W 14
#define NBOX   512
#define CH     256
#define IMH    200
#define IMW    200
#define PLANE  (IMH * IMW)               // 40000
#define PER_BOX (CH * CROP_H * CROP_W)   // 50176
#define CPT    4                         // channels (outputs) per thread
#define ELEMS_PER_BOX (PER_BOX / CPT)    // 12544 = 49 * 256
#define BLOCKS_PER_BOX (ELEMS_PER_BOX / 256)  // 49

// Grid (x=box fastest, y=chunk): resident blocks cover a thin channel slice of
// ALL boxes -> few-MB working set, L2/L3 resident, image fetched ~once.
// Each thread computes 4 outputs (same box/gy/gx, channels c, c+64, c+128,
// c+192): 8 independent 8B gathers in flight per thread for latency hiding.
__global__ __launch_bounds__(256) void CropAndResize_60146722013533_kernel(
    const float* __restrict__ image,
    const float* __restrict__ boxes,
    const int*   __restrict__ box_idx,
    float*       __restrict__ out)
{
    const int n = blockIdx.x;          // box index (fastest dispatch dim)
    const int t = threadIdx.x;

    __shared__ int   sy0[CROP_H], sy1[CROP_H], sx0[CROP_W], sx1[CROP_W];
    __shared__ float sly[CROP_H], slx[CROP_W];
    __shared__ int   svy[CROP_H], svx[CROP_W];
    __shared__ int   sb;

    if (t < CROP_H + CROP_W) {
        const float by1 = boxes[n * 4 + 0];
        const float bx1 = boxes[n * 4 + 1];
        const float by2 = boxes[n * 4 + 2];
        const float bx2 = boxes[n * 4 + 3];
        if (t < CROP_H) {
            const int gy = t;
            float h_scale = (by2 - by1) * (float)(IMH - 1) / (float)(CROP_H - 1);
            float in_y = by1 * (float)(IMH - 1) + (float)gy * h_scale;
            svy[gy] = (in_y >= 0.0f && in_y <= (float)(IMH - 1)) ? 1 : 0;
            float yf = floorf(in_y);
            sly[gy] = in_y - yf;
            sy0[gy] = (int)fminf(fmaxf(yf, 0.0f), (float)(IMH - 1));
            sy1[gy] = (int)fminf(fmaxf(ceilf(in_y), 0.0f), (float)(IMH - 1));
        } else {
            const int gx = t - CROP_H;
            float w_scale = (bx2 - bx1) * (float)(IMW - 1) / (float)(CROP_W - 1);
            float in_x = bx1 * (float)(IMW - 1) + (float)gx * w_scale;
            svx[gx] = (in_x >= 0.0f && in_x <= (float)(IMW - 1)) ? 1 : 0;
            float xf = floorf(in_x);
            slx[gx] = in_x - xf;
            sx0[gx] = (int)fminf(fmaxf(xf, 0.0f), (float)(IMW - 1));
            sx1[gx] = (int)fminf(fmaxf(ceilf(in_x), 0.0f), (float)(IMW - 1));
        }
    }
    if (t == 0) sb = box_idx[n];
    __syncthreads();

    // elem within first channel-quarter: [0, 12544); c in [0,64)
    const int elem = blockIdx.y * 256 + t;
    const int c  = elem / (CROP_H * CROP_W);
    const int r  = elem - c * (CROP_H * CROP_W);
    const int gy = r / CROP_W;
    const int gx = r - gy * CROP_W;

    const int y0  = sy0[gy];
    const int y1i = sy1[gy];
    const int x0  = sx0[gx];
    const int x1i = sx1[gx];
    const float ly = sly[gy];
    const float lx = slx[gx];
    const int masked = !(svy[gy] & svx[gx]);

    // x-pair anchor: both x0 and x1i lie in {xb, xb+1}
    const int xb = (x0 < IMW - 2) ? x0 : (IMW - 2);
    const int offT = y0  * IMW + xb;
    const int offB = y1i * IMW + xb;

    const float* p0 = image + ((size_t)(sb * CH + c)) * (size_t)PLANE;
    const size_t cstep = (size_t)64 * PLANE;

    // 8 independent 8B loads — maximize outstanding vmem before first use
    float2 vt0, vb0, vt1, vb1, vt2, vb2, vt3, vb3;
    __builtin_memcpy(&vt0, p0 + offT,             8);
    __builtin_memcpy(&vb0, p0 + offB,             8);
    __builtin_memcpy(&vt1, p0 + cstep + offT,     8);
    __builtin_memcpy(&vb1, p0 + cstep + offB,     8);
    __builtin_memcpy(&vt2, p0 + 2 * cstep + offT, 8);
    __builtin_memcpy(&vb2, p0 + 2 * cstep + offB, 8);
    __builtin_memcpy(&vt3, p0 + 3 * cstep + offT, 8);
    __builtin_memcpy(&vb3, p0 + 3 * cstep + offB, 8);

    const bool selL = (x0 == xb);    // tl/bl take .x else .y
    const bool selR = (x1i == xb);   // tr/br take .x else .y

    float* const outp = out + (size_t)n * PER_BOX + (size_t)c * (CROP_H * CROP_W) + r;

    {
        const float tl = selL ? vt0.x : vt0.y, tr = selR ? vt0.x : vt0.y;
        const float bl = selL ? vb0.x : vb0.y, br = selR ? vb0.x : vb0.y;
        const float top = tl + (tr - tl) * lx;
        const float bot = bl + (br - bl) * lx;
        float v = top + (bot - top) * ly;
        outp[0] = masked ? 0.0f : v;
    }
    {
        const float tl = selL ? vt1.x : vt1.y, tr = selR ? vt1.x : vt1.y;
        const float bl = selL ? vb1.x : vb1.y, br = selR ? vb1.x : vb1.y;
        const float top = tl + (tr - tl) * lx;
        const float bot = bl + (br - bl) * lx;
        float v = top + (bot - top) * ly;
        outp[64 * (CROP_H * CROP_W)] = masked ? 0.0f : v;
    }
    {
        const float tl = selL ? vt2.x : vt2.y, tr = selR ? vt2.x : vt2.y;
        const float bl = selL ? vb2.x : vb2.y, br = selR ? vb2.x : vb2.y;
        const float top = tl + (tr - tl) * lx;
        const float bot = bl + (br - bl) * lx;
        float v = top + (bot - top) * ly;
        outp[128 * (CROP_H * CROP_W)] = masked ? 0.0f : v;
    }
    {
        const float tl = selL ? vt3.x : vt3.y, tr = selR ? vt3.x : vt3.y;
        const float bl = selL ? vb3.x : vb3.y, br = selR ? vb3.x : vb3.y;
        const float top = tl + (tr - tl) * lx;
        const float bot = bl + (br - bl) * lx;
        float v = top + (bot - top) * ly;
        outp[192 * (CROP_H * CROP_W)] = masked ? 0.0f : v;
    }
}

extern "C" void kernel_launch(void* const* d_in, const int* in_sizes, int n_in,
                              void* d_out, int out_size, void* d_ws, size_t ws_size,
                              hipStream_t stream) {
    const float* image   = (const float*)d_in[0];
    const float* boxes   = (const float*)d_in[1];
    const int*   box_idx = (const int*)d_in[2];
    float* out = (float*)d_out;

    dim3 grid(NBOX, BLOCKS_PER_BOX, 1);   // x = box (fastest), y = chunk
    dim3 block(256, 1, 1);
    CropAndResize_60146722013533_kernel<<<grid, block, 0, stream>>>(image, boxes, box_idx, out);
}